// Round 6
// baseline (248.720 us; speedup 1.0000x reference)
//
#include <hip/hip_runtime.h>

typedef __attribute__((ext_vector_type(4))) float f32x4;
typedef __attribute__((ext_vector_type(8))) short short8;
typedef __attribute__((ext_vector_type(4))) unsigned int u32x4;
typedef __attribute__((ext_vector_type(2))) unsigned int u32x2;
typedef unsigned short u16;
typedef unsigned int u32;

__device__ __forceinline__ u16 f2bf(float f) {
  u32 u = __builtin_bit_cast(u32, f);
  u += 0x7fffu + ((u >> 16) & 1u);
  return (u16)(u >> 16);
}
__device__ __forceinline__ u16 f2bf_t(float f) {
  return (u16)(__builtin_bit_cast(u32, f) >> 16);
}

__device__ __forceinline__ void gl2lds16(const u16* g, const u16* l) {
  __builtin_amdgcn_global_load_lds(
      (const __attribute__((address_space(1))) u32*)g,
      (__attribute__((address_space(3))) u32*)(u32)(unsigned long long)l,
      16, 0, 0);
}

// ---------------------------------------------------------------------------
// Fused prep (unchanged): casts x/ctx to bf16, transposes+casts 3 weights.
// ---------------------------------------------------------------------------
__device__ __forceinline__ void cast_body(const float* __restrict__ s,
                                          u16* __restrict__ d, int blk,
                                          int tid) {
  long i = (long)blk * 256 + tid;
  const f32x4* sp = (const f32x4*)(s + i * 8);
  f32x4 a = sp[0], b = sp[1];
  u16 t[8];
#pragma unroll
  for (int j = 0; j < 4; j++) {
    t[j] = f2bf(a[j]);
    t[4 + j] = f2bf(b[j]);
  }
  *(u32x4*)(d + i * 8) = *(u32x4*)t;
}

__device__ __forceinline__ void transpose_body(const float* __restrict__ W,
                                               u16* __restrict__ WT, int K,
                                               int N, int k0, int n0, int tid,
                                               u16* T) {
#pragma unroll
  for (int i = 0; i < 4; i++) {
    int c = tid + 256 * i;
    int row = c >> 4;
    int ch = c & 15;
    f32x4 f = *(const f32x4*)(W + (long)(k0 + row) * N + n0 + ch * 4);
#pragma unroll
    for (int j = 0; j < 4; j++) T[(ch * 4 + j) * 72 + row] = f2bf(f[j]);
  }
  __syncthreads();
#pragma unroll
  for (int i = 0; i < 2; i++) {
    int c = tid + 256 * i;
    int row = c >> 3;
    int ch = c & 7;
    u32x4 v = *(u32x4*)&T[row * 72 + ch * 8];
    *(u32x4*)(WT + (long)(n0 + row) * K + k0 + ch * 8) = v;
  }
}

__global__ __launch_bounds__(256) void prep(
    const float* __restrict__ x, const float* __restrict__ ctx,
    const float* __restrict__ Wq, const float* __restrict__ Wkv,
    const float* __restrict__ Wo, u16* __restrict__ xb,
    u16* __restrict__ ctxb, u16* __restrict__ wqT, u16* __restrict__ wkvT,
    u16* __restrict__ woT) {
  __shared__ __align__(16) u16 T[64 * 72];
  const int b = blockIdx.x, tid = threadIdx.x;
  if (b < 2048) {
    cast_body(x, xb, b, tid);
  } else if (b < 3584) {
    cast_body(ctx, ctxb, b - 2048, tid);
  } else if (b < 3840) {
    int idx = b - 3584;
    transpose_body(Wq, wqT, 1024, 1024, (idx >> 4) * 64, (idx & 15) * 64, tid, T);
  } else if (b < 4224) {
    int idx = b - 3840;
    transpose_body(Wkv, wkvT, 768, 2048, (idx >> 5) * 64, (idx & 31) * 64, tid, T);
  } else {
    int idx = b - 4224;
    transpose_body(Wo, woT, 1024, 1024, (idx >> 4) * 64, (idx & 15) * 64, tid, T);
  }
}

// ---------------------------------------------------------------------------
// 128x128 GEMM core: BK=64, 4 waves in 2x2 (64x64 each), global_load_lds
// width-16 staging, XOR chunk-swizzle on global source. Kstride = row stride
// of A/Bt (elements); Klen = contraction length for this block.
// ---------------------------------------------------------------------------
__device__ __forceinline__ void gemm128_core(
    const u16* __restrict__ A, const u16* __restrict__ Bt, int Kstride,
    int Klen, long brow, long bcol, int tid, u16* As, u16* Bs,
    f32x4 (&acc)[4][4]) {
  const int lane = tid & 63, wv = tid >> 6;
  const int l15 = lane & 15, quad = lane >> 4;
  const int wr = (wv >> 1) * 64, wc = (wv & 1) * 64;
  const int sr = lane >> 3, sc = lane & 7;
  const int csw = ((sc ^ sr) & 7) * 8;

  const u16* ag[4];
  const u16* bg[4];
  const u16* al[4];
  const u16* bl[4];
#pragma unroll
  for (int n = 0; n < 4; n++) {
    int row = wv * 32 + n * 8;
    ag[n] = A + (brow + row + sr) * (long)Kstride + csw;
    al[n] = &As[row * 64];
    bg[n] = Bt + (bcol + row + sr) * (long)Kstride + csw;
    bl[n] = &Bs[row * 64];
  }

  for (int kt = 0; kt < Klen; kt += 64) {
    __syncthreads();
#pragma unroll
    for (int n = 0; n < 4; n++) gl2lds16(ag[n] + kt, al[n]);
#pragma unroll
    for (int n = 0; n < 4; n++) gl2lds16(bg[n] + kt, bl[n]);
    __syncthreads();
#pragma unroll
    for (int kk = 0; kk < 2; kk++) {
      short8 af[4], bf[4];
#pragma unroll
      for (int i = 0; i < 4; i++) {
        int row = wr + i * 16 + l15;
        af[i] = *(short8*)&As[row * 64 + (((kk * 4 + quad) ^ (row & 7)) << 3)];
      }
#pragma unroll
      for (int j = 0; j < 4; j++) {
        int row = wc + j * 16 + l15;
        bf[j] = *(short8*)&Bs[row * 64 + (((kk * 4 + quad) ^ (row & 7)) << 3)];
      }
#pragma unroll
      for (int i = 0; i < 4; i++)
#pragma unroll
        for (int j = 0; j < 4; j++)
          acc[i][j] = __builtin_amdgcn_mfma_f32_16x16x32_bf16(
              af[i], bf[j], acc[i][j], 0, 0, 0);
    }
  }
}

// ---------------------------------------------------------------------------
// Fused Q-proj + KV-proj (unchanged layout math).
//   bid <  256: Q  = xb @ wqT -> Qb (bf16, *qscale)
//   bid >= 256: KV = ctxb @ wkvT -> K row-major / V^T permuted+swizzled
// ---------------------------------------------------------------------------
__global__ __launch_bounds__(256, 3) void fused_qkv(
    const u16* __restrict__ xb, const u16* __restrict__ ctxb,
    const u16* __restrict__ wqT, const u16* __restrict__ wkvT,
    u16* __restrict__ Qb, u16* __restrict__ Kb, u16* __restrict__ Vtg,
    float qscale) {
  __shared__ __align__(16) u16 As[128 * 64];
  __shared__ __align__(16) u16 Bs[128 * 64];
  const int tid = threadIdx.x;
  const int lane = tid & 63, wv = tid >> 6;
  const int l15 = lane & 15, quad = lane >> 4;
  const int wr = (wv >> 1) * 64, wc = (wv & 1) * 64;

  f32x4 acc[4][4];
#pragma unroll
  for (int i = 0; i < 4; i++)
#pragma unroll
    for (int j = 0; j < 4; j++) acc[i][j] = (f32x4){0.f, 0.f, 0.f, 0.f};

  int bid = blockIdx.x;
  if (bid < 256) {
    long brow = (long)(bid >> 3) * 128, bcol = (long)(bid & 7) * 128;
    gemm128_core(xb, wqT, 1024, 1024, brow, bcol, tid, As, Bs, acc);
#pragma unroll
    for (int i = 0; i < 4; i++)
#pragma unroll
      for (int j = 0; j < 4; j++)
#pragma unroll
        for (int r = 0; r < 4; r++) {
          long row = brow + wr + i * 16 + quad * 4 + r;
          long col = bcol + wc + j * 16 + l15;
          Qb[row * 1024 + col] = f2bf(acc[i][j][r] * qscale);
        }
  } else {
    bid -= 256;
    long brow = (long)(bid >> 4) * 128, bcol = (long)(bid & 15) * 128;
    gemm128_core(ctxb, wkvT, 768, 768, brow, bcol, tid, As, Bs, acc);
    if (bcol < 1024) {
#pragma unroll
      for (int i = 0; i < 4; i++)
#pragma unroll
        for (int j = 0; j < 4; j++)
#pragma unroll
          for (int r = 0; r < 4; r++) {
            long row = brow + wr + i * 16 + quad * 4 + r;
            long col = bcol + wc + j * 16 + l15;
            Kb[row * 1024 + col] = f2bf(acc[i][j][r]);
          }
    } else {
#pragma unroll
      for (int i = 0; i < 4; i++)
#pragma unroll
        for (int j = 0; j < 4; j++) {
          long mg = brow + wr + i * 16 + quad * 4;
          int bb = (int)(mg >> 11);
          int mm = (int)(mg & 2047);
          int tau = mm >> 6, lm = mm & 63;
          int dcol = (int)(bcol + wc + j * 16 + l15) - 1024;
          int h = dcol >> 6, d = dcol & 63;
          int c = ((lm >> 5) & 1) * 4 + ((lm >> 2) & 3);
          int eoff = tau * 64 + (((c ^ (d & 7)) << 3)) + (((lm >> 4) & 1) << 2);
          u32 lo = (u32)f2bf(acc[i][j][0]) | ((u32)f2bf(acc[i][j][1]) << 16);
          u32 hi = (u32)f2bf(acc[i][j][2]) | ((u32)f2bf(acc[i][j][3]) << 16);
          u32x2 v = {lo, hi};
          *(u32x2*)&Vtg[(((long)(bb * 16 + h) * 64 + d) * 2048) + eoff] = v;
        }
    }
  }
}

// ---------------------------------------------------------------------------
// O-projection GEMM, split-K x2: grid (8, 32, 2), each block does K=512 and
// atomicAdd-accumulates fp32 into C (zero-initialized via hipMemsetAsync).
// float add of exactly 2 terms is commutative -> deterministic result.
// ---------------------------------------------------------------------------
__global__ __launch_bounds__(256, 3) void gemm_o(
    const u16* __restrict__ A, const u16* __restrict__ Bt,
    float* __restrict__ C) {
  __shared__ __align__(16) u16 As[128 * 64];
  __shared__ __align__(16) u16 Bs[128 * 64];
  const int tid = threadIdx.x;
  const int lane = tid & 63, wv = tid >> 6;
  const int l15 = lane & 15, quad = lane >> 4;
  const int wr = (wv >> 1) * 64, wc = (wv & 1) * 64;
  long brow = (long)blockIdx.y * 128, bcol = (long)blockIdx.x * 128;
  int k0 = blockIdx.z * 512;

  f32x4 acc[4][4];
#pragma unroll
  for (int i = 0; i < 4; i++)
#pragma unroll
    for (int j = 0; j < 4; j++) acc[i][j] = (f32x4){0.f, 0.f, 0.f, 0.f};

  gemm128_core(A + k0, Bt + k0, 1024, 512, brow, bcol, tid, As, Bs, acc);

#pragma unroll
  for (int i = 0; i < 4; i++)
#pragma unroll
    for (int j = 0; j < 4; j++)
#pragma unroll
      for (int r = 0; r < 4; r++) {
        long row = brow + wr + i * 16 + quad * 4 + r;
        long col = bcol + wc + j * 16 + l15;
        atomicAdd(&C[row * 1024 + col], acc[i][j][r]);
      }
}

// ---------------------------------------------------------------------------
// Flash attention v5: NO LDS, NO barriers. K and V fragments loaded directly
// from global (per-lane 16B b128), V from the pre-permuted Vtg. S^T trick
// keeps P in registers. 1-deep K prefetch (ping-pong), V single-buffered
// (its latency is covered by the 16 S^T MFMAs + exp2 pack). Fixed-shift
// softmax exp2(s-24); row-sum via all-ones B-frag.
// grid (16, 32), block 256 (4 waves x 32 q-rows).
// ---------------------------------------------------------------------------
__global__ __launch_bounds__(256, 2) void attn_kernel(
    const u16* __restrict__ Q, const u16* __restrict__ Kg,
    const u16* __restrict__ Vtg, u16* __restrict__ AO) {
  const int tid = threadIdx.x;
  const int lane = tid & 63, wave = tid >> 6;
  const int l15 = lane & 15, quad = lane >> 4;
  const int bh = blockIdx.y;
  const int b = bh >> 4, h = bh & 15;
  const long qrow0 = (long)b * 2048 + blockIdx.x * 128;

  short8 qf[2][2];
#pragma unroll
  for (int qt = 0; qt < 2; qt++)
#pragma unroll
    for (int kk = 0; kk < 2; kk++)
      qf[qt][kk] = *(const short8*)&Q[(qrow0 + wave * 32 + qt * 16 + l15) * 1024 +
                                      h * 64 + kk * 32 + quad * 8];

  f32x4 O[2][5];
#pragma unroll
  for (int qt = 0; qt < 2; qt++)
#pragma unroll
    for (int dt = 0; dt < 5; dt++) O[qt][dt] = (f32x4){0.f, 0.f, 0.f, 0.f};

  u32x4 ones_u = {0x3F803F80u, 0x3F803F80u, 0x3F803F80u, 0x3F803F80u};
  short8 ones = __builtin_bit_cast(short8, ones_u);

  // per-lane fragment base pointers
  const u16* kb = Kg + (long)b * 2048 * 1024 + h * 64;
  const u16* vtg = Vtg + (long)(b * 16 + h) * 64 * 2048;
  const u16* kfb[2][4];
  const u16* vfb[2][4];
#pragma unroll
  for (int kk = 0; kk < 2; kk++)
#pragma unroll
    for (int t = 0; t < 4; t++) {
      int row = t * 16 + l15;
      kfb[kk][t] = kb + (long)row * 1024 + kk * 32 + quad * 8;
      vfb[kk][t] = vtg + (long)row * 2048 + (((kk * 4 + quad) ^ (row & 7)) << 3);
    }

  auto load_k = [&](short8(&kf)[2][4], int mt) {
#pragma unroll
    for (int kk = 0; kk < 2; kk++)
#pragma unroll
      for (int t = 0; t < 4; t++)
        kf[kk][t] = *(const short8*)(kfb[kk][t] + (long)mt * 1024);
  };

  auto step = [&](short8(&kc)[2][4], short8(&kn)[2][4], int mt) {
    // V fragments for current tile (single-buffer; covered by S^T latency)
    short8 vf[2][4];
#pragma unroll
    for (int kk = 0; kk < 2; kk++)
#pragma unroll
      for (int dt = 0; dt < 4; dt++)
        vf[kk][dt] = *(const short8*)(vfb[kk][dt] + mt);
    // prefetch next K tile
    if (mt + 64 < 2048) load_k(kn, mt + 64);

    // S^T: rows m (quad*4+r within m-subtile), cols q (l15)
    f32x4 s[4][2];
#pragma unroll
    for (int m4 = 0; m4 < 4; m4++)
#pragma unroll
      for (int qt = 0; qt < 2; qt++) s[m4][qt] = (f32x4){0.f, 0.f, 0.f, 0.f};
#pragma unroll
    for (int kk = 0; kk < 2; kk++)
#pragma unroll
      for (int m4 = 0; m4 < 4; m4++)
#pragma unroll
        for (int qt = 0; qt < 2; qt++)
          s[m4][qt] = __builtin_amdgcn_mfma_f32_16x16x32_bf16(
              kc[kk][m4], qf[qt][kk], s[m4][qt], 0, 0, 0);

    // p = exp2(s-24) packed straight into PV A-fragments; O += P @ V
#pragma unroll
    for (int kk = 0; kk < 2; kk++) {
#pragma unroll
      for (int qt = 0; qt < 2; qt++) {
        u32 w[4];
#pragma unroll
        for (int half = 0; half < 2; half++) {
          f32x4 sv = s[2 * kk + half][qt];
          u32 lo = (u32)f2bf_t(__builtin_amdgcn_exp2f(sv[0] - 24.f)) |
                   ((u32)f2bf_t(__builtin_amdgcn_exp2f(sv[1] - 24.f)) << 16);
          u32 hi = (u32)f2bf_t(__builtin_amdgcn_exp2f(sv[2] - 24.f)) |
                   ((u32)f2bf_t(__builtin_amdgcn_exp2f(sv[3] - 24.f)) << 16);
          w[half * 2] = lo;
          w[half * 2 + 1] = hi;
        }
        short8 pa = __builtin_bit_cast(short8, *(u32x4*)w);
#pragma unroll
        for (int dt = 0; dt < 4; dt++)
          O[qt][dt] = __builtin_amdgcn_mfma_f32_16x16x32_bf16(
              pa, vf[kk][dt], O[qt][dt], 0, 0, 0);
        O[qt][4] = __builtin_amdgcn_mfma_f32_16x16x32_bf16(
            pa, ones, O[qt][4], 0, 0, 0);
      }
    }
  };

  short8 ka[2][4], kbuf[2][4];
  load_k(ka, 0);
  for (int mt = 0; mt < 2048; mt += 128) {
    step(ka, kbuf, mt);
    step(kbuf, ka, mt + 64);
  }

#pragma unroll
  for (int qt = 0; qt < 2; qt++) {
    float inv[4];
#pragma unroll
    for (int r = 0; r < 4; r++) inv[r] = 1.f / O[qt][4][r];
#pragma unroll
    for (int dt = 0; dt < 4; dt++)
#pragma unroll
      for (int r = 0; r < 4; r++) {
        long row = qrow0 + wave * 32 + qt * 16 + quad * 4 + r;
        int col = h * 64 + dt * 16 + l15;
        AO[row * 1024 + col] = f2bf(O[qt][dt][r] * inv[r]);
      }
  }
}

// ---------------------------------------------------------------------------
extern "C" void kernel_launch(void* const* d_in, const int* in_sizes, int n_in,
                              void* d_out, int out_size, void* d_ws,
                              size_t ws_size, hipStream_t stream) {
  const float* x = (const float*)d_in[0];     // [2,2048,1024]
  const float* ctx = (const float*)d_in[1];   // [2,2048,768]
  const float* Wq = (const float*)d_in[2];    // [1024,1024]
  const float* Wkv = (const float*)d_in[3];   // [768,2048]
  const float* Wo = (const float*)d_in[4];    // [1024,1024]
  float* out = (float*)d_out;                 // [2,2048,1024] fp32

  u16* ws = (u16*)d_ws;
  u16* wqT = ws;                       // [1024][1024]
  u16* wkvT = wqT + 1048576;           // [2048][768]
  u16* woT = wkvT + 1572864;           // [1024][1024]
  u16* Qb = woT + 1048576;             // [4096][1024] bf16 (q-scaled)
  u16* Kb = Qb + 4194304;              // [4096][1024] bf16
  u16* Vtg = Kb + 4194304;             // [2][16][64][2048] bf16 (V^T perm+swz)
  u16* xb = Vtg + 4194304;             // [4096][1024] bf16 (aliased: AOb)
  u16* ctxb = xb + 4194304;            // [4096][768]  bf16
  u16* AOb = xb;  // xb dead after fused_qkv

  const float qscale = 0.125f * 1.4426950408889634f;  // Dh^-0.5 * log2(e)

  hipMemsetAsync(out, 0, (size_t)4096 * 1024 * sizeof(float), stream);

  prep<<<dim3(4480), 256, 0, stream>>>(x, ctx, Wq, Wkv, Wo, xb, ctxb, wqT,
                                       wkvT, woT);

  fused_qkv<<<dim3(768), 256, 0, stream>>>(xb, ctxb, wqT, wkvT, Qb, Kb, Vtg,
                                           qscale);

  attn_kernel<<<dim3(16, 32), 256, 0, stream>>>(Qb, Kb, Vtg, AOb);

  gemm_o<<<dim3(8, 32, 2), 256, 0, stream>>>(AOb, woT, out);
}

// Round 7
// 183.666 us; speedup vs baseline: 1.3542x; 1.3542x over previous
//
#include <hip/hip_runtime.h>

typedef __attribute__((ext_vector_type(4))) float f32x4;
typedef __attribute__((ext_vector_type(8))) short short8;
typedef __attribute__((ext_vector_type(4))) unsigned int u32x4;
typedef unsigned short u16;
typedef unsigned int u32;
typedef unsigned long long u64;

__device__ __forceinline__ u16 f2bf(float f) {
  u32 u = __builtin_bit_cast(u32, f);
  u += 0x7fffu + ((u >> 16) & 1u);
  return (u16)(u >> 16);
}
__device__ __forceinline__ u16 f2bf_t(float f) {
  return (u16)(__builtin_bit_cast(u32, f) >> 16);
}

__device__ __forceinline__ void gl2lds16(const u16* g, const u16* l) {
  __builtin_amdgcn_global_load_lds(
      (const __attribute__((address_space(1))) u32*)g,
      (__attribute__((address_space(3))) u32*)(u32)(u64)l,
      16, 0, 0);
}

// ---------------------------------------------------------------------------
// Fused prep (unchanged): casts x/ctx to bf16, transposes+casts 3 weights.
// ---------------------------------------------------------------------------
__device__ __forceinline__ void cast_body(const float* __restrict__ s,
                                          u16* __restrict__ d, int blk,
                                          int tid) {
  long i = (long)blk * 256 + tid;
  const f32x4* sp = (const f32x4*)(s + i * 8);
  f32x4 a = sp[0], b = sp[1];
  u16 t[8];
#pragma unroll
  for (int j = 0; j < 4; j++) {
    t[j] = f2bf(a[j]);
    t[4 + j] = f2bf(b[j]);
  }
  *(u32x4*)(d + i * 8) = *(u32x4*)t;
}

__device__ __forceinline__ void transpose_body(const float* __restrict__ W,
                                               u16* __restrict__ WT, int K,
                                               int N, int k0, int n0, int tid,
                                               u16* T) {
#pragma unroll
  for (int i = 0; i < 4; i++) {
    int c = tid + 256 * i;
    int row = c >> 4;
    int ch = c & 15;
    f32x4 f = *(const f32x4*)(W + (long)(k0 + row) * N + n0 + ch * 4);
#pragma unroll
    for (int j = 0; j < 4; j++) T[(ch * 4 + j) * 72 + row] = f2bf(f[j]);
  }
  __syncthreads();
#pragma unroll
  for (int i = 0; i < 2; i++) {
    int c = tid + 256 * i;
    int row = c >> 3;
    int ch = c & 7;
    u32x4 v = *(u32x4*)&T[row * 72 + ch * 8];
    *(u32x4*)(WT + (long)(n0 + row) * K + k0 + ch * 8) = v;
  }
}

__global__ __launch_bounds__(256) void prep(
    const float* __restrict__ x, const float* __restrict__ ctx,
    const float* __restrict__ Wq, const float* __restrict__ Wkv,
    const float* __restrict__ Wo, u16* __restrict__ xb,
    u16* __restrict__ ctxb, u16* __restrict__ wqT, u16* __restrict__ wkvT,
    u16* __restrict__ woT) {
  __shared__ __align__(16) u16 T[64 * 72];
  const int b = blockIdx.x, tid = threadIdx.x;
  if (b < 2048) {
    cast_body(x, xb, b, tid);
  } else if (b < 3584) {
    cast_body(ctx, ctxb, b - 2048, tid);
  } else if (b < 3840) {
    int idx = b - 3584;
    transpose_body(Wq, wqT, 1024, 1024, (idx >> 4) * 64, (idx & 15) * 64, tid, T);
  } else if (b < 4224) {
    int idx = b - 3840;
    transpose_body(Wkv, wkvT, 768, 2048, (idx >> 5) * 64, (idx & 31) * 64, tid, T);
  } else {
    int idx = b - 4224;
    transpose_body(Wo, woT, 1024, 1024, (idx >> 4) * 64, (idx & 15) * 64, tid, T);
  }
}

// ---------------------------------------------------------------------------
// 128x128 GEMM core (m97-class), unchanged.
// ---------------------------------------------------------------------------
__device__ __forceinline__ void gemm128_core(
    const u16* __restrict__ A, const u16* __restrict__ Bt, int Kstride,
    int Klen, long brow, long bcol, int tid, u16* As, u16* Bs,
    f32x4 (&acc)[4][4]) {
  const int lane = tid & 63, wv = tid >> 6;
  const int l15 = lane & 15, quad = lane >> 4;
  const int wr = (wv >> 1) * 64, wc = (wv & 1) * 64;
  const int sr = lane >> 3, sc = lane & 7;
  const int csw = ((sc ^ sr) & 7) * 8;

  const u16* ag[4];
  const u16* bg[4];
  const u16* al[4];
  const u16* bl[4];
#pragma unroll
  for (int n = 0; n < 4; n++) {
    int row = wv * 32 + n * 8;
    ag[n] = A + (brow + row + sr) * (long)Kstride + csw;
    al[n] = &As[row * 64];
    bg[n] = Bt + (bcol + row + sr) * (long)Kstride + csw;
    bl[n] = &Bs[row * 64];
  }

  for (int kt = 0; kt < Klen; kt += 64) {
    __syncthreads();
#pragma unroll
    for (int n = 0; n < 4; n++) gl2lds16(ag[n] + kt, al[n]);
#pragma unroll
    for (int n = 0; n < 4; n++) gl2lds16(bg[n] + kt, bl[n]);
    __syncthreads();
#pragma unroll
    for (int kk = 0; kk < 2; kk++) {
      short8 af[4], bf[4];
#pragma unroll
      for (int i = 0; i < 4; i++) {
        int row = wr + i * 16 + l15;
        af[i] = *(short8*)&As[row * 64 + (((kk * 4 + quad) ^ (row & 7)) << 3)];
      }
#pragma unroll
      for (int j = 0; j < 4; j++) {
        int row = wc + j * 16 + l15;
        bf[j] = *(short8*)&Bs[row * 64 + (((kk * 4 + quad) ^ (row & 7)) << 3)];
      }
#pragma unroll
      for (int i = 0; i < 4; i++)
#pragma unroll
        for (int j = 0; j < 4; j++)
          acc[i][j] = __builtin_amdgcn_mfma_f32_16x16x32_bf16(
              af[i], bf[j], acc[i][j], 0, 0, 0);
    }
  }
}

// ---------------------------------------------------------------------------
// Fused Q-proj + KV-proj. KV epilogue now emits K and V in
// FRAGMENT-INSTRUCTION-MAJOR global layout (per bh, per 64-m tile, 8 blocks
// of 1KB whose 64 16B-chunks are exactly one wave's MFMA operand fragments):
//   Kfrag[bh][mt][kk][t][lane=quad*16+l15][e]  = K[m=t*16+l15][d=kk*32+quad*8+e]
//   Vfrag[bh][mt][kk][dt][lane=quad*16+l15][j] =
//       V[m=kk*32+(j>>2)*16+quad*4+(j&3)][d=dt*16+l15]
// Written via a 16KB LDS transpose (reusing As) in two m-rounds, then
// 16B/lane coalesced global stores.
// ---------------------------------------------------------------------------
__global__ __launch_bounds__(256, 3) void fused_qkv(
    const u16* __restrict__ xb, const u16* __restrict__ ctxb,
    const u16* __restrict__ wqT, const u16* __restrict__ wkvT,
    u16* __restrict__ Qb, u16* __restrict__ Kfrag, u16* __restrict__ Vfrag,
    float qscale) {
  __shared__ __align__(16) u16 As[128 * 64];
  __shared__ __align__(16) u16 Bs[128 * 64];
  const int tid = threadIdx.x;
  const int lane = tid & 63, wv = tid >> 6;
  const int l15 = lane & 15, quad = lane >> 4;
  const int wr = (wv >> 1) * 64, wc = (wv & 1) * 64;

  f32x4 acc[4][4];
#pragma unroll
  for (int i = 0; i < 4; i++)
#pragma unroll
    for (int j = 0; j < 4; j++) acc[i][j] = (f32x4){0.f, 0.f, 0.f, 0.f};

  int bid = blockIdx.x;
  if (bid < 256) {
    long brow = (long)(bid >> 3) * 128, bcol = (long)(bid & 7) * 128;
    gemm128_core(xb, wqT, 1024, 1024, brow, bcol, tid, As, Bs, acc);
#pragma unroll
    for (int i = 0; i < 4; i++)
#pragma unroll
      for (int j = 0; j < 4; j++)
#pragma unroll
        for (int r = 0; r < 4; r++) {
          long row = brow + wr + i * 16 + quad * 4 + r;
          long col = bcol + wc + j * 16 + l15;
          Qb[row * 1024 + col] = f2bf(acc[i][j][r] * qscale);
        }
    return;
  }

  bid -= 256;
  long brow = (long)(bid >> 4) * 128, bcol = (long)(bid & 15) * 128;
  gemm128_core(ctxb, wkvT, 768, 768, brow, bcol, tid, As, Bs, acc);

  const bool is_k = (bcol < 1024);
  __syncthreads();  // all frag reads of As/Bs done; reuse As as transpose buf
#pragma unroll
  for (int round = 0; round < 2; round++) {
    if ((wv >> 1) == round) {
      if (is_k) {
        // element (m_loc = i*16+quad*4+r, d = j*16+l15) of head (wv&1)
#pragma unroll
        for (int i = 0; i < 4; i++)
#pragma unroll
          for (int j = 0; j < 4; j++) {
            int d = j * 16 + l15;
            int off = (wv & 1) * 4096 + ((d >> 5) * 4 + i) * 512 +
                      (((d >> 3) & 3) * 16 + quad * 4) * 8 + (d & 7);
#pragma unroll
            for (int r = 0; r < 4; r++) As[off + r * 8] = f2bf(acc[i][j][r]);
          }
      } else {
        // V: kk=i>>1, dt=j, quad_b=quad, elem=(i&1)*4+r  (r -> 4 consec u16)
#pragma unroll
        for (int i = 0; i < 4; i++)
#pragma unroll
          for (int j = 0; j < 4; j++) {
            int off = (wv & 1) * 4096 + ((i >> 1) * 4 + j) * 512 +
                      (quad * 16 + l15) * 8 + (i & 1) * 4;
            u16 t4[4];
#pragma unroll
            for (int r = 0; r < 4; r++) t4[r] = f2bf(acc[i][j][r]);
            *(u64*)&As[off] = *(const u64*)t4;
          }
      }
    }
    __syncthreads();
    long mg = brow + round * 64;
    int b_ = (int)(mg >> 11), mt = (int)((mg >> 6) & 31);
#pragma unroll
    for (int h2 = 0; h2 < 2; h2++) {
      int h = (int)((is_k ? bcol : bcol - 1024) >> 6) + h2;
      u16* dst = (is_k ? Kfrag : Vfrag) + ((long)(b_ * 16 + h) * 32 + mt) * 4096;
#pragma unroll
      for (int p = 0; p < 2; p++) {
        int c = p * 256 + tid;  // 0..511 chunks of 16B
        *(u32x4*)(dst + c * 8) = *(u32x4*)&As[h2 * 4096 + c * 8];
      }
    }
    __syncthreads();
  }
}

// ---------------------------------------------------------------------------
// O-projection GEMM (round-5 form: no split-K, no atomics). 128x128 tiles.
// ---------------------------------------------------------------------------
__global__ __launch_bounds__(256, 3) void gemm_o(
    const u16* __restrict__ A, const u16* __restrict__ Bt,
    float* __restrict__ C) {
  __shared__ __align__(16) u16 As[128 * 64];
  __shared__ __align__(16) u16 Bs[128 * 64];
  const int tid = threadIdx.x;
  const int lane = tid & 63, wv = tid >> 6;
  const int l15 = lane & 15, quad = lane >> 4;
  const int wr = (wv >> 1) * 64, wc = (wv & 1) * 64;
  long brow = (long)blockIdx.y * 128, bcol = (long)blockIdx.x * 128;

  f32x4 acc[4][4];
#pragma unroll
  for (int i = 0; i < 4; i++)
#pragma unroll
    for (int j = 0; j < 4; j++) acc[i][j] = (f32x4){0.f, 0.f, 0.f, 0.f};

  gemm128_core(A, Bt, 1024, 1024, brow, bcol, tid, As, Bs, acc);

#pragma unroll
  for (int i = 0; i < 4; i++)
#pragma unroll
    for (int j = 0; j < 4; j++)
#pragma unroll
      for (int r = 0; r < 4; r++) {
        long row = brow + wr + i * 16 + quad * 4 + r;
        long col = bcol + wc + j * 16 + l15;
        C[row * 1024 + col] = acc[i][j][r];
      }
}

// ---------------------------------------------------------------------------
// Flash attention v7: NO LDS, NO barriers, and every K/V load instruction is
// a fully-coalesced 1KB block (fragment-instruction-major Kfrag/Vfrag).
// K double-buffered (1-tile prefetch); V issued at iter start, consumed
// after the 16 S^T MFMAs. S^T trick keeps P in registers; fixed-shift
// softmax exp2(s-24); row-sum via all-ones B-frag.
// grid (16, 32), block 256 (4 waves x 32 q-rows).
// ---------------------------------------------------------------------------
__global__ __launch_bounds__(256, 2) void attn_kernel(
    const u16* __restrict__ Q, const u16* __restrict__ Kfrag,
    const u16* __restrict__ Vfrag, u16* __restrict__ AO) {
  const int tid = threadIdx.x;
  const int lane = tid & 63, wave = tid >> 6;
  const int l15 = lane & 15, quad = lane >> 4;
  const int bh = blockIdx.y;
  const int b = bh >> 4, h = bh & 15;
  const long qrow0 = (long)b * 2048 + blockIdx.x * 128;

  short8 qf[2][2];
#pragma unroll
  for (int qt = 0; qt < 2; qt++)
#pragma unroll
    for (int kk = 0; kk < 2; kk++)
      qf[qt][kk] = *(const short8*)&Q[(qrow0 + wave * 32 + qt * 16 + l15) * 1024 +
                                      h * 64 + kk * 32 + quad * 8];

  f32x4 O[2][5];
#pragma unroll
  for (int qt = 0; qt < 2; qt++)
#pragma unroll
    for (int dt = 0; dt < 5; dt++) O[qt][dt] = (f32x4){0.f, 0.f, 0.f, 0.f};

  u32x4 ones_u = {0x3F803F80u, 0x3F803F80u, 0x3F803F80u, 0x3F803F80u};
  short8 ones = __builtin_bit_cast(short8, ones_u);

  const u16* kbase = Kfrag + (long)bh * 32 * 4096 + lane * 8;
  const u16* vbase = Vfrag + (long)bh * 32 * 4096 + lane * 8;

  auto load_k = [&](short8(&kf)[2][4], int tile) {
    const u16* kt = kbase + (long)tile * 4096;
#pragma unroll
    for (int kk = 0; kk < 2; kk++)
#pragma unroll
      for (int t = 0; t < 4; t++)
        kf[kk][t] = *(const short8*)(kt + (kk * 4 + t) * 512);
  };

  auto step = [&](short8(&kc)[2][4], short8(&kn)[2][4], int tile) {
    // V fragments for current tile (coalesced 1KB per instr)
    short8 vf[2][4];
    const u16* vt = vbase + (long)tile * 4096;
#pragma unroll
    for (int kk = 0; kk < 2; kk++)
#pragma unroll
      for (int dt = 0; dt < 4; dt++)
        vf[kk][dt] = *(const short8*)(vt + (kk * 4 + dt) * 512);
    // prefetch next K tile
    if (tile + 1 < 32) load_k(kn, tile + 1);

    // S^T: rows m (quad*4+r within m-subtile), cols q (l15)
    f32x4 s[4][2];
#pragma unroll
    for (int m4 = 0; m4 < 4; m4++)
#pragma unroll
      for (int qt = 0; qt < 2; qt++) s[m4][qt] = (f32x4){0.f, 0.f, 0.f, 0.f};
#pragma unroll
    for (int kk = 0; kk < 2; kk++)
#pragma unroll
      for (int m4 = 0; m4 < 4; m4++)
#pragma unroll
        for (int qt = 0; qt < 2; qt++)
          s[m4][qt] = __builtin_amdgcn_mfma_f32_16x16x32_bf16(
              kc[kk][m4], qf[qt][kk], s[m4][qt], 0, 0, 0);

    // p = exp2(s-24) packed straight into PV A-fragments; O += P @ V
#pragma unroll
    for (int kk = 0; kk < 2; kk++) {
#pragma unroll
      for (int qt = 0; qt < 2; qt++) {
        u32 w[4];
#pragma unroll
        for (int half = 0; half < 2; half++) {
          f32x4 sv = s[2 * kk + half][qt];
          u32 lo = (u32)f2bf_t(__builtin_amdgcn_exp2f(sv[0] - 24.f)) |
                   ((u32)f2bf_t(__builtin_amdgcn_exp2f(sv[1] - 24.f)) << 16);
          u32 hi = (u32)f2bf_t(__builtin_amdgcn_exp2f(sv[2] - 24.f)) |
                   ((u32)f2bf_t(__builtin_amdgcn_exp2f(sv[3] - 24.f)) << 16);
          w[half * 2] = lo;
          w[half * 2 + 1] = hi;
        }
        short8 pa = __builtin_bit_cast(short8, *(u32x4*)w);
#pragma unroll
        for (int dt = 0; dt < 4; dt++)
          O[qt][dt] = __builtin_amdgcn_mfma_f32_16x16x32_bf16(
              pa, vf[kk][dt], O[qt][dt], 0, 0, 0);
        O[qt][4] = __builtin_amdgcn_mfma_f32_16x16x32_bf16(
            pa, ones, O[qt][4], 0, 0, 0);
      }
    }
  };

  short8 ka[2][4], kb2[2][4];
  load_k(ka, 0);
  for (int tile = 0; tile < 32; tile += 2) {
    step(ka, kb2, tile);
    step(kb2, ka, tile + 1);
  }

#pragma unroll
  for (int qt = 0; qt < 2; qt++) {
    float inv[4];
#pragma unroll
    for (int r = 0; r < 4; r++) inv[r] = 1.f / O[qt][4][r];
#pragma unroll
    for (int dt = 0; dt < 4; dt++)
#pragma unroll
      for (int r = 0; r < 4; r++) {
        long row = qrow0 + wave * 32 + qt * 16 + quad * 4 + r;
        int col = h * 64 + dt * 16 + l15;
        AO[row * 1024 + col] = f2bf(O[qt][dt][r] * inv[r]);
      }
  }
}

// ---------------------------------------------------------------------------
extern "C" void kernel_launch(void* const* d_in, const int* in_sizes, int n_in,
                              void* d_out, int out_size, void* d_ws,
                              size_t ws_size, hipStream_t stream) {
  const float* x = (const float*)d_in[0];     // [2,2048,1024]
  const float* ctx = (const float*)d_in[1];   // [2,2048,768]
  const float* Wq = (const float*)d_in[2];    // [1024,1024]
  const float* Wkv = (const float*)d_in[3];   // [768,2048]
  const float* Wo = (const float*)d_in[4];    // [1024,1024]
  float* out = (float*)d_out;                 // [2,2048,1024] fp32

  u16* ws = (u16*)d_ws;
  u16* wqT = ws;                       // [1024][1024]
  u16* wkvT = wqT + 1048576;           // [2048][768]
  u16* woT = wkvT + 1572864;           // [1024][1024]
  u16* Qb = woT + 1048576;             // [4096][1024] bf16 (q-scaled)
  u16* Kfrag = Qb + 4194304;           // [32][32][4096] fragment-major K
  u16* Vfrag = Kfrag + 4194304;        // [32][32][4096] fragment-major V
  u16* xb = Vfrag + 4194304;           // [4096][1024] bf16 (aliased: AOb)
  u16* ctxb = xb + 4194304;            // [4096][768]  bf16
  u16* AOb = xb;  // xb dead after fused_qkv

  const float qscale = 0.125f * 1.4426950408889634f;  // Dh^-0.5 * log2(e)

  prep<<<dim3(4480), 256, 0, stream>>>(x, ctx, Wq, Wkv, Wo, xb, ctxb, wqT,
                                       wkvT, woT);

  fused_qkv<<<dim3(768), 256, 0, stream>>>(xb, ctxb, wqT, wkvT, Qb, Kfrag,
                                           Vfrag, qscale);

  attn_kernel<<<dim3(16, 32), 256, 0, stream>>>(Qb, Kfrag, Vfrag, AOb);

  gemm_o<<<dim3(8, 32), 256, 0, stream>>>(AOb, woT, out);
}